// Round 11
// baseline (136.593 us; speedup 1.0000x reference)
//
#include <hip/hip_runtime.h>
#include <hip/hip_bf16.h>

#define NPTS   131072
#define NNODES 2048
#define KSEL   32

// ---- knn decomposition ----
#define TKNN   256                 // threads per knn block
#define PPT    4                   // points per thread
#define PPG_K  (TKNN * PPT)        // 1024 points per knn group
#define NGRP_K (NPTS / PPG_K)      // 128 knn groups
#define NCHUNK 16                  // node chunks (block-uniform -> s_load)
#define CHN    (NNODES / NCHUNK)   // 128 nodes per chunk

// ---- grouping/scatter decomposition ----
#define GSZ    512                 // points per stability group
#define NG     (NPTS / GSZ)        // 256 groups

typedef unsigned int uint;
typedef unsigned short u16;
typedef unsigned long long u64;

// order-preserving fp32 -> u32 (handles tiny-negative cancellation results)
__device__ __forceinline__ uint f2ord(float d) {
    uint b = __float_as_uint(d);
    return (b & 0x80000000u) ? ~b : (b | 0x80000000u);
}
__device__ __forceinline__ float ord2f(uint t) {
    uint b = (t & 0x80000000u) ? (t ^ 0x80000000u) : ~t;
    return __uint_as_float(b);
}

// --- K0: init knnres to max keys; first 2048 threads also pack nodes {x,y,z,|n|^2} ---
__global__ __launch_bounds__(256) void prep_init(const float* __restrict__ nodes,
                                                 float4* __restrict__ n4,
                                                 u64* __restrict__ knnres) {
    int i = blockIdx.x * 256 + threadIdx.x;
    knnres[i] = ~0ull;
    if (i < NNODES) {
        float x = nodes[3 * i], y = nodes[3 * i + 1], z = nodes[3 * i + 2];
        // |n|^2 with numpy's mul-then-add rounding
        float nn = __fadd_rn(__fadd_rn(__fmul_rn(x, x), __fmul_rn(y, y)), __fmul_rn(z, z));
        n4[i] = make_float4(x, y, z, nn);
    }
}

// One node (scalars SX..SW in SGPRs) against 4 points held in operand VGPRs.
// d = (pp + fma(nz,z, fma(ny,y, nx*x))) + nn  == ref (pp - 2*dot) + nn bit-exactly.
// 20 arith + 12 select + 1 idx bump = 33 VALU.
#define NODE4(SX, SY, SZ, SW) \
    "v_mul_f32 v0, " SX ", %[nx0]\n\t" \
    "v_mul_f32 v1, " SX ", %[nx1]\n\t" \
    "v_mul_f32 v2, " SX ", %[nx2]\n\t" \
    "v_mul_f32 v3, " SX ", %[nx3]\n\t" \
    "v_fma_f32 v0, " SY ", %[ny0], v0\n\t" \
    "v_fma_f32 v1, " SY ", %[ny1], v1\n\t" \
    "v_fma_f32 v2, " SY ", %[ny2], v2\n\t" \
    "v_fma_f32 v3, " SY ", %[ny3], v3\n\t" \
    "v_fma_f32 v0, " SZ ", %[nz0], v0\n\t" \
    "v_fma_f32 v1, " SZ ", %[nz1], v1\n\t" \
    "v_fma_f32 v2, " SZ ", %[nz2], v2\n\t" \
    "v_fma_f32 v3, " SZ ", %[nz3], v3\n\t" \
    "v_add_f32 v0, %[pp0], v0\n\t" \
    "v_add_f32 v1, %[pp1], v1\n\t" \
    "v_add_f32 v2, %[pp2], v2\n\t" \
    "v_add_f32 v3, %[pp3], v3\n\t" \
    "v_add_f32 v0, " SW ", v0\n\t" \
    "v_add_f32 v1, " SW ", v1\n\t" \
    "v_add_f32 v2, " SW ", v2\n\t" \
    "v_add_f32 v3, " SW ", v3\n\t" \
    "v_cmp_lt_f32 vcc, v0, %[b0]\n\t" \
    "v_cndmask_b32 %[b0], %[b0], v0, vcc\n\t" \
    "v_cndmask_b32 %[i0], %[i0], %[vj], vcc\n\t" \
    "v_cmp_lt_f32 vcc, v1, %[b1]\n\t" \
    "v_cndmask_b32 %[b1], %[b1], v1, vcc\n\t" \
    "v_cndmask_b32 %[i1], %[i1], %[vj], vcc\n\t" \
    "v_cmp_lt_f32 vcc, v2, %[b2]\n\t" \
    "v_cndmask_b32 %[b2], %[b2], v2, vcc\n\t" \
    "v_cndmask_b32 %[i2], %[i2], %[vj], vcc\n\t" \
    "v_cmp_lt_f32 vcc, v3, %[b3]\n\t" \
    "v_cndmask_b32 %[b3], %[b3], v3, vcc\n\t" \
    "v_cndmask_b32 %[i3], %[i3], %[vj], vcc\n\t" \
    "v_add_u32 %[vj], 1, %[vj]\n\t"

// --- K1: partial 1-NN, 4 pts/thread; ping-pong s_load_dwordx16 prefetch ---
// Each s_waitcnt lgkmcnt(0) drains a load issued one 4-node compute block
// (~260 cyc of VALU) earlier -> SMEM/L2 latency hidden under compute.
// Strict < ascending jj = first-occurrence argmin; cross-chunk merge via
// u64 atomicMin on (ord(d2) << 32 | node) keys.
__global__ __launch_bounds__(256) void knn_part(const float* __restrict__ pts,
                                                const float4* __restrict__ n4,
                                                u64* __restrict__ knnres) {
    int bid = blockIdx.x;
    int c   = bid & (NCHUNK - 1);            // block-uniform chunk
    int g   = bid >> 4;                      // knn point group
    int t   = threadIdx.x;

    float pp[PPT], nx[PPT], ny[PPT], nz[PPT];
    #pragma unroll
    for (int q = 0; q < PPT; ++q) {
        int pid = g * PPG_K + q * TKNN + t;
        float p0 = pts[3 * pid], p1 = pts[3 * pid + 1], p2 = pts[3 * pid + 2];
        pp[q] = __fadd_rn(__fadd_rn(__fmul_rn(p0, p0), __fmul_rn(p1, p1)),
                          __fmul_rn(p2, p2));
        nx[q] = __fmul_rn(-2.0f, p0);        // exact
        ny[q] = __fmul_rn(-2.0f, p1);
        nz[q] = __fmul_rn(-2.0f, p2);
    }

    const float4* np = n4 + c * CHN;         // block-uniform base
    float b0 = 3.4e38f, b1 = 3.4e38f, b2 = 3.4e38f, b3 = 3.4e38f;
    uint  i0 = 0, i1 = 0, i2 = 0, i3 = 0;
    uint  vj = 0;

    // 16 iterations x 8 nodes. Buffers: s[36:51] / s[52:67] (4 nodes = 64 B each).
    // Last iteration prefetches 64 B past the chunk end (ws table padded).
    asm volatile(
        "s_mov_b64 s[12:13], %[np]\n\t"
        "s_mov_b32 s8, 0\n\t"
        "s_load_dwordx16 s[36:51], s[12:13], 0x0\n\t"
        "1:\n\t"
        "s_waitcnt lgkmcnt(0)\n\t"
        "s_load_dwordx16 s[52:67], s[12:13], 0x40\n\t"
        NODE4("s36", "s37", "s38", "s39")
        NODE4("s40", "s41", "s42", "s43")
        NODE4("s44", "s45", "s46", "s47")
        NODE4("s48", "s49", "s50", "s51")
        "s_waitcnt lgkmcnt(0)\n\t"
        "s_load_dwordx16 s[36:51], s[12:13], 0x80\n\t"
        NODE4("s52", "s53", "s54", "s55")
        NODE4("s56", "s57", "s58", "s59")
        NODE4("s60", "s61", "s62", "s63")
        NODE4("s64", "s65", "s66", "s67")
        "s_add_u32 s12, s12, 0x80\n\t"
        "s_addc_u32 s13, s13, 0\n\t"
        "s_add_u32 s8, s8, 1\n\t"
        "s_cmp_lt_u32 s8, 16\n\t"
        "s_cbranch_scc1 1b\n\t"
        "s_waitcnt lgkmcnt(0)\n\t"          // drain dangling prefetch
        : [b0]"+v"(b0), [b1]"+v"(b1), [b2]"+v"(b2), [b3]"+v"(b3),
          [i0]"+v"(i0), [i1]"+v"(i1), [i2]"+v"(i2), [i3]"+v"(i3),
          [vj]"+v"(vj)
        : [np]"s"(np),
          [nx0]"v"(nx[0]), [nx1]"v"(nx[1]), [nx2]"v"(nx[2]), [nx3]"v"(nx[3]),
          [ny0]"v"(ny[0]), [ny1]"v"(ny[1]), [ny2]"v"(ny[2]), [ny3]"v"(ny[3]),
          [nz0]"v"(nz[0]), [nz1]"v"(nz[1]), [nz2]"v"(nz[2]), [nz3]"v"(nz[3]),
          [pp0]"v"(pp[0]), [pp1]"v"(pp[1]), [pp2]"v"(pp[2]), [pp3]"v"(pp[3])
        : "s8", "s12", "s13",
          "s36", "s37", "s38", "s39", "s40", "s41", "s42", "s43",
          "s44", "s45", "s46", "s47", "s48", "s49", "s50", "s51",
          "s52", "s53", "s54", "s55", "s56", "s57", "s58", "s59",
          "s60", "s61", "s62", "s63", "s64", "s65", "s66", "s67",
          "v0", "v1", "v2", "v3", "vcc", "scc", "memory");

    float best[PPT] = {b0, b1, b2, b3};
    uint  bi[PPT]   = {i0, i1, i2, i3};
    #pragma unroll
    for (int h = 0; h < PPT; ++h) {
        int pid = g * PPG_K + h * TKNN + t;
        u64 key = ((u64)f2ord(best[h]) << 32) | (uint)(c * CHN + bi[h]);
        atomicMin(&knnres[pid], key);        // min key == (min d2, then min node idx)
    }
}

// --- K2: decode winners, write d2/id/pcd, per-group u16 histogram, zero patch ---
__global__ __launch_bounds__(256) void merge_hist(const u64* __restrict__ knnres,
                                                  float* __restrict__ out_d2,
                                                  float* __restrict__ out_id,
                                                  int* __restrict__ pcd,
                                                  u16* __restrict__ hist16,
                                                  float* __restrict__ patch) {
    __shared__ uint lh[NNODES];
    int g = blockIdx.x, t = threadIdx.x;
    patch[(size_t)g * 256 + t] = 0.0f;       // 256x256 = full 65536-float patch zeroed
    for (int i = t; i < NNODES; i += 256) lh[i] = 0;
    __syncthreads();

    #pragma unroll
    for (int q = 0; q < GSZ / 256; ++q) {
        int pid = g * GSZ + q * 256 + t;
        u64 key = knnres[pid];
        uint bi = (uint)key;                 // low 32: node index
        float d = ord2f((uint)(key >> 32));  // exact d2 decode
        atomicAdd(&lh[bi], 1u);
        out_d2[pid] = d;
        out_id[pid] = (float)bi;             // exact: bi < 2^24
        pcd[pid]    = (int)bi;
    }
    __syncthreads();
    for (int i = t; i < NNODES; i += 256)
        hist16[(size_t)g * NNODES + i] = (u16)lh[i];   // contiguous stores
}

// --- K3: per-node exclusive prefix across the 256 groups; offs in [node][group] ---
__global__ __launch_bounds__(256) void scan_offs(const u16* __restrict__ hist16,
                                                 uint* __restrict__ offs) {
    int t = threadIdx.x, lane = t & 63, wv = t >> 6;
    int node = blockIdx.x * 4 + wv;

    uint v0 = hist16[(size_t)(4 * lane + 0) * NNODES + node];
    uint v1 = hist16[(size_t)(4 * lane + 1) * NNODES + node];
    uint v2 = hist16[(size_t)(4 * lane + 2) * NNODES + node];
    uint v3 = hist16[(size_t)(4 * lane + 3) * NNODES + node];
    uint s = v0 + v1 + v2 + v3;
    uint a = s;
    #pragma unroll
    for (int d = 1; d < 64; d <<= 1) {
        uint y = __shfl_up(a, d, 64);
        if (lane >= d) a += y;
    }
    uint base = a - s;                        // exclusive across lanes
    uint4 o = make_uint4(base, base + v0, base + v0 + v1, base + v0 + v1 + v2);
    *(uint4*)(offs + (size_t)node * NG + 4 * lane) = o;   // contiguous 16B store
}

// --- K4: stable scatter of first-32 point indices per node ---
__global__ __launch_bounds__(256) void scatter_patch(const int* __restrict__ pcd,
                                                     const uint* __restrict__ offs,
                                                     float* __restrict__ patch) {
    __shared__ int ids[GSZ];
    int g = blockIdx.x, t = threadIdx.x;
    ids[t]       = pcd[g * GSZ + t];
    ids[256 + t] = pcd[g * GSZ + 256 + t];
    __syncthreads();

    int i0 = t, i1 = 256 + t;
    int my0 = ids[i0], my1 = ids[i1];
    int r0 = 0, r1 = 0;
    #pragma unroll 8
    for (int j = 0; j < GSZ; ++j) {
        int id = ids[j];                      // broadcast LDS read, conflict-free
        r0 += (j < i0 && id == my0) ? 1 : 0;
        r1 += (j < i1 && id == my1) ? 1 : 0;
    }
    uint rk0 = offs[(size_t)my0 * NG + g] + (uint)r0;
    uint rk1 = offs[(size_t)my1 * NG + g] + (uint)r1;
    if (rk0 < KSEL) patch[(size_t)my0 * KSEL + rk0] = (float)(g * GSZ + i0);
    if (rk1 < KSEL) patch[(size_t)my1 * KSEL + rk1] = (float)(g * GSZ + i1);
}

extern "C" void kernel_launch(void* const* d_in, const int* in_sizes, int n_in,
                              void* d_out, int out_size, void* d_ws, size_t ws_size,
                              hipStream_t stream) {
    const float* pts   = (const float*)d_in[0];
    const float* nodes = (const float*)d_in[1];

    float* out       = (float*)d_out;
    float* out_d2    = out;                  // 131072 floats
    float* out_id    = out + NPTS;           // 131072 floats
    float* out_patch = out + 2 * NPTS;       // 65536 floats

    // workspace: ~4.6 MB (n4 table has >=64B slack after it for the asm overshoot)
    char* ws = (char*)d_ws;
    u64*   knnres = (u64*) ws;                               // 1 MB   (131072 x u64)
    u16*   hist16 = (u16*) (ws + (1 << 20));                 // 1 MB   (256 x 2048 u16)
    uint*  offs   = (uint*) (ws + (2 << 20));                // 2 MB   (2048 x 256 u32)
    int*   pcd    = (int*)  (ws + (4 << 20));                // 512 KB
    float4* n4    = (float4*)(ws + (4 << 20) + (512 << 10)); // 32 KB + slack

    prep_init<<<NPTS / 256, 256, 0, stream>>>(nodes, n4, knnres);
    knn_part<<<NGRP_K * NCHUNK, TKNN, 0, stream>>>(pts, n4, knnres);
    merge_hist<<<NG, 256, 0, stream>>>(knnres, out_d2, out_id, pcd, hist16, out_patch);
    scan_offs<<<NNODES / 4, 256, 0, stream>>>(hist16, offs);
    scatter_patch<<<NG, 256, 0, stream>>>(pcd, offs, out_patch);
}

// Round 12
// 134.678 us; speedup vs baseline: 1.0142x; 1.0142x over previous
//
#include <hip/hip_runtime.h>
#include <hip/hip_bf16.h>

#define NPTS   131072
#define NNODES 2048
#define KSEL   32

// ---- knn decomposition: 512 blocks x 1024 threads (16 waves) ----
#define TKNN   1024                // threads per knn block
#define WPB    16                  // waves per block
#define PPT    4                   // points per thread
#define NCHUNK 16                  // node chunks; chunk = wave-uniform -> s_load
#define CHN    (NNODES / NCHUNK)   // 128 nodes per chunk
#define NPG    512                 // point groups of 256 points (one per wave-set)

// ---- grouping/scatter decomposition ----
#define GSZ    512                 // points per stability group
#define NG     (NPTS / GSZ)        // 256 groups

typedef unsigned int uint;
typedef unsigned short u16;
typedef unsigned long long u64;

// order-preserving fp32 -> u32 (handles tiny-negative cancellation results)
__device__ __forceinline__ uint f2ord(float d) {
    uint b = __float_as_uint(d);
    return (b & 0x80000000u) ? ~b : (b | 0x80000000u);
}
__device__ __forceinline__ float ord2f(uint t) {
    uint b = (t & 0x80000000u) ? (t ^ 0x80000000u) : ~t;
    return __uint_as_float(b);
}

// --- K0: init knnres to max keys; first 2048 threads also pack nodes {x,y,z,|n|^2} ---
__global__ __launch_bounds__(256) void prep_init(const float* __restrict__ nodes,
                                                 float4* __restrict__ n4,
                                                 u64* __restrict__ knnres) {
    int i = blockIdx.x * 256 + threadIdx.x;
    knnres[i] = ~0ull;
    if (i < NNODES) {
        float x = nodes[3 * i], y = nodes[3 * i + 1], z = nodes[3 * i + 2];
        // |n|^2 with numpy's mul-then-add rounding
        float nn = __fadd_rn(__fadd_rn(__fmul_rn(x, x), __fmul_rn(y, y)), __fmul_rn(z, z));
        n4[i] = make_float4(x, y, z, nn);
    }
}

// One node (scalars SX..SW) vs 4 points. d = (pp + fma(nz,z, fma(ny,y, nx*x))) + nn
// == ref (pp - 2*dot) + nn bit-exactly. Selects use 4 distinct SGPR-pair masks
// (no vcc serialization): 4 independent cmps, then 8 cndmasks on settled masks.
#define NODE4(SX, SY, SZ, SW) \
    "v_mul_f32 v0, " SX ", %[nx0]\n\t" \
    "v_mul_f32 v1, " SX ", %[nx1]\n\t" \
    "v_mul_f32 v2, " SX ", %[nx2]\n\t" \
    "v_mul_f32 v3, " SX ", %[nx3]\n\t" \
    "v_fma_f32 v0, " SY ", %[ny0], v0\n\t" \
    "v_fma_f32 v1, " SY ", %[ny1], v1\n\t" \
    "v_fma_f32 v2, " SY ", %[ny2], v2\n\t" \
    "v_fma_f32 v3, " SY ", %[ny3], v3\n\t" \
    "v_fma_f32 v0, " SZ ", %[nz0], v0\n\t" \
    "v_fma_f32 v1, " SZ ", %[nz1], v1\n\t" \
    "v_fma_f32 v2, " SZ ", %[nz2], v2\n\t" \
    "v_fma_f32 v3, " SZ ", %[nz3], v3\n\t" \
    "v_add_f32 v0, %[pp0], v0\n\t" \
    "v_add_f32 v1, %[pp1], v1\n\t" \
    "v_add_f32 v2, %[pp2], v2\n\t" \
    "v_add_f32 v3, %[pp3], v3\n\t" \
    "v_add_f32 v0, " SW ", v0\n\t" \
    "v_add_f32 v1, " SW ", v1\n\t" \
    "v_add_f32 v2, " SW ", v2\n\t" \
    "v_add_f32 v3, " SW ", v3\n\t" \
    "v_cmp_lt_f32 s[4:5], v0, %[b0]\n\t" \
    "v_cmp_lt_f32 s[6:7], v1, %[b1]\n\t" \
    "v_cmp_lt_f32 s[8:9], v2, %[b2]\n\t" \
    "v_cmp_lt_f32 s[10:11], v3, %[b3]\n\t" \
    "v_cndmask_b32 %[b0], %[b0], v0, s[4:5]\n\t" \
    "v_cndmask_b32 %[i0], %[i0], %[vj], s[4:5]\n\t" \
    "v_cndmask_b32 %[b1], %[b1], v1, s[6:7]\n\t" \
    "v_cndmask_b32 %[i1], %[i1], %[vj], s[6:7]\n\t" \
    "v_cndmask_b32 %[b2], %[b2], v2, s[8:9]\n\t" \
    "v_cndmask_b32 %[i2], %[i2], %[vj], s[8:9]\n\t" \
    "v_cndmask_b32 %[b3], %[b3], v3, s[10:11]\n\t" \
    "v_cndmask_b32 %[i3], %[i3], %[vj], s[10:11]\n\t" \
    "v_add_u32 %[vj], 1, %[vj]\n\t"

// --- K1: partial 1-NN, 4 pts/thread; 16-wave blocks; ping-pong s_load prefetch ---
// Strict < ascending jj = first-occurrence argmin; cross-chunk merge via
// u64 atomicMin on (ord(d2) << 32 | node) keys.
__global__ __launch_bounds__(1024) void knn_part(const float* __restrict__ pts,
                                                 const float4* __restrict__ n4,
                                                 u64* __restrict__ knnres) {
    int t    = threadIdx.x;
    int lane = t & 63;
    int w    = t >> 6;                        // wave in block
    int gw   = blockIdx.x * WPB + w;          // global wave id [0, 8192)
    int c    = __builtin_amdgcn_readfirstlane(gw & (NCHUNK - 1));  // wave-uniform chunk
    int pg   = gw >> 4;                       // point group [0, 512) of 256 points

    float pp[PPT], nx[PPT], ny[PPT], nz[PPT];
    #pragma unroll
    for (int q = 0; q < PPT; ++q) {
        int pid = pg * 256 + q * 64 + lane;   // consecutive lanes -> coalesced
        float p0 = pts[3 * pid], p1 = pts[3 * pid + 1], p2 = pts[3 * pid + 2];
        pp[q] = __fadd_rn(__fadd_rn(__fmul_rn(p0, p0), __fmul_rn(p1, p1)),
                          __fmul_rn(p2, p2));
        nx[q] = __fmul_rn(-2.0f, p0);         // exact
        ny[q] = __fmul_rn(-2.0f, p1);
        nz[q] = __fmul_rn(-2.0f, p2);
    }

    const float4* np = n4 + c * CHN;          // wave-uniform base (scalar)
    float b0 = 3.4e38f, b1 = 3.4e38f, b2 = 3.4e38f, b3 = 3.4e38f;
    uint  i0 = 0, i1 = 0, i2 = 0, i3 = 0;
    uint  vj = 0;

    // 16 iterations x 8 nodes. Buffers: s[36:51]/s[52:67] (4 nodes = 64 B each).
    // Each waitcnt drains a load issued one 4-node compute block earlier.
    // Last iteration prefetches 64 B past the chunk end (table has slack).
    asm volatile(
        "s_mov_b64 s[12:13], %[np]\n\t"
        "s_mov_b32 s14, 0\n\t"
        "s_load_dwordx16 s[36:51], s[12:13], 0x0\n\t"
        "1:\n\t"
        "s_waitcnt lgkmcnt(0)\n\t"
        "s_load_dwordx16 s[52:67], s[12:13], 0x40\n\t"
        NODE4("s36", "s37", "s38", "s39")
        NODE4("s40", "s41", "s42", "s43")
        NODE4("s44", "s45", "s46", "s47")
        NODE4("s48", "s49", "s50", "s51")
        "s_waitcnt lgkmcnt(0)\n\t"
        "s_load_dwordx16 s[36:51], s[12:13], 0x80\n\t"
        NODE4("s52", "s53", "s54", "s55")
        NODE4("s56", "s57", "s58", "s59")
        NODE4("s60", "s61", "s62", "s63")
        NODE4("s64", "s65", "s66", "s67")
        "s_add_u32 s12, s12, 0x80\n\t"
        "s_addc_u32 s13, s13, 0\n\t"
        "s_add_u32 s14, s14, 1\n\t"
        "s_cmp_lt_u32 s14, 16\n\t"
        "s_cbranch_scc1 1b\n\t"
        "s_waitcnt lgkmcnt(0)\n\t"            // drain dangling prefetch
        : [b0]"+v"(b0), [b1]"+v"(b1), [b2]"+v"(b2), [b3]"+v"(b3),
          [i0]"+v"(i0), [i1]"+v"(i1), [i2]"+v"(i2), [i3]"+v"(i3),
          [vj]"+v"(vj)
        : [np]"s"(np),
          [nx0]"v"(nx[0]), [nx1]"v"(nx[1]), [nx2]"v"(nx[2]), [nx3]"v"(nx[3]),
          [ny0]"v"(ny[0]), [ny1]"v"(ny[1]), [ny2]"v"(ny[2]), [ny3]"v"(ny[3]),
          [nz0]"v"(nz[0]), [nz1]"v"(nz[1]), [nz2]"v"(nz[2]), [nz3]"v"(nz[3]),
          [pp0]"v"(pp[0]), [pp1]"v"(pp[1]), [pp2]"v"(pp[2]), [pp3]"v"(pp[3])
        : "s4", "s5", "s6", "s7", "s8", "s9", "s10", "s11", "s12", "s13", "s14",
          "s36", "s37", "s38", "s39", "s40", "s41", "s42", "s43",
          "s44", "s45", "s46", "s47", "s48", "s49", "s50", "s51",
          "s52", "s53", "s54", "s55", "s56", "s57", "s58", "s59",
          "s60", "s61", "s62", "s63", "s64", "s65", "s66", "s67",
          "v0", "v1", "v2", "v3", "vcc", "scc", "memory");

    float best[PPT] = {b0, b1, b2, b3};
    uint  bi[PPT]   = {i0, i1, i2, i3};
    #pragma unroll
    for (int h = 0; h < PPT; ++h) {
        int pid = pg * 256 + h * 64 + lane;
        u64 key = ((u64)f2ord(best[h]) << 32) | (uint)(c * CHN + bi[h]);
        atomicMin(&knnres[pid], key);         // min key == (min d2, then min node idx)
    }
}

// --- K2: decode winners, write d2/id/pcd, per-group u16 histogram, zero patch ---
__global__ __launch_bounds__(256) void merge_hist(const u64* __restrict__ knnres,
                                                  float* __restrict__ out_d2,
                                                  float* __restrict__ out_id,
                                                  int* __restrict__ pcd,
                                                  u16* __restrict__ hist16,
                                                  float* __restrict__ patch) {
    __shared__ uint lh[NNODES];
    int g = blockIdx.x, t = threadIdx.x;
    patch[(size_t)g * 256 + t] = 0.0f;        // 256x256 = full 65536-float patch zeroed
    for (int i = t; i < NNODES; i += 256) lh[i] = 0;
    __syncthreads();

    #pragma unroll
    for (int q = 0; q < GSZ / 256; ++q) {
        int pid = g * GSZ + q * 256 + t;
        u64 key = knnres[pid];
        uint bi = (uint)key;                  // low 32: node index
        float d = ord2f((uint)(key >> 32));   // exact d2 decode
        atomicAdd(&lh[bi], 1u);
        out_d2[pid] = d;
        out_id[pid] = (float)bi;              // exact: bi < 2^24
        pcd[pid]    = (int)bi;
    }
    __syncthreads();
    for (int i = t; i < NNODES; i += 256)
        hist16[(size_t)g * NNODES + i] = (u16)lh[i];   // contiguous stores
}

// --- K3: per-node exclusive prefix across the 256 groups; offs in [node][group] ---
__global__ __launch_bounds__(256) void scan_offs(const u16* __restrict__ hist16,
                                                 uint* __restrict__ offs) {
    int t = threadIdx.x, lane = t & 63, wv = t >> 6;
    int node = blockIdx.x * 4 + wv;

    uint v0 = hist16[(size_t)(4 * lane + 0) * NNODES + node];
    uint v1 = hist16[(size_t)(4 * lane + 1) * NNODES + node];
    uint v2 = hist16[(size_t)(4 * lane + 2) * NNODES + node];
    uint v3 = hist16[(size_t)(4 * lane + 3) * NNODES + node];
    uint s = v0 + v1 + v2 + v3;
    uint a = s;
    #pragma unroll
    for (int d = 1; d < 64; d <<= 1) {
        uint y = __shfl_up(a, d, 64);
        if (lane >= d) a += y;
    }
    uint base = a - s;                        // exclusive across lanes
    uint4 o = make_uint4(base, base + v0, base + v0 + v1, base + v0 + v1 + v2);
    *(uint4*)(offs + (size_t)node * NG + 4 * lane) = o;   // contiguous 16B store
}

// --- K4: stable scatter of first-32 point indices per node ---
__global__ __launch_bounds__(256) void scatter_patch(const int* __restrict__ pcd,
                                                     const uint* __restrict__ offs,
                                                     float* __restrict__ patch) {
    __shared__ int ids[GSZ];
    int g = blockIdx.x, t = threadIdx.x;
    ids[t]       = pcd[g * GSZ + t];
    ids[256 + t] = pcd[g * GSZ + 256 + t];
    __syncthreads();

    int i0 = t, i1 = 256 + t;
    int my0 = ids[i0], my1 = ids[i1];
    int r0 = 0, r1 = 0;
    #pragma unroll 8
    for (int j = 0; j < GSZ; ++j) {
        int id = ids[j];                      // broadcast LDS read, conflict-free
        r0 += (j < i0 && id == my0) ? 1 : 0;
        r1 += (j < i1 && id == my1) ? 1 : 0;
    }
    uint rk0 = offs[(size_t)my0 * NG + g] + (uint)r0;
    uint rk1 = offs[(size_t)my1 * NG + g] + (uint)r1;
    if (rk0 < KSEL) patch[(size_t)my0 * KSEL + rk0] = (float)(g * GSZ + i0);
    if (rk1 < KSEL) patch[(size_t)my1 * KSEL + rk1] = (float)(g * GSZ + i1);
}

extern "C" void kernel_launch(void* const* d_in, const int* in_sizes, int n_in,
                              void* d_out, int out_size, void* d_ws, size_t ws_size,
                              hipStream_t stream) {
    const float* pts   = (const float*)d_in[0];
    const float* nodes = (const float*)d_in[1];

    float* out       = (float*)d_out;
    float* out_d2    = out;                   // 131072 floats
    float* out_id    = out + NPTS;            // 131072 floats
    float* out_patch = out + 2 * NPTS;        // 65536 floats

    // workspace: ~4.6 MB (n4 table has >=64B slack after it for the asm overshoot)
    char* ws = (char*)d_ws;
    u64*   knnres = (u64*) ws;                               // 1 MB   (131072 x u64)
    u16*   hist16 = (u16*) (ws + (1 << 20));                 // 1 MB   (256 x 2048 u16)
    uint*  offs   = (uint*) (ws + (2 << 20));                // 2 MB   (2048 x 256 u32)
    int*   pcd    = (int*)  (ws + (4 << 20));                // 512 KB
    float4* n4    = (float4*)(ws + (4 << 20) + (512 << 10)); // 32 KB + slack

    prep_init<<<NPTS / 256, 256, 0, stream>>>(nodes, n4, knnres);
    knn_part<<<NPTS / (TKNN * PPT) * NCHUNK, TKNN, 0, stream>>>(pts, n4, knnres);
    merge_hist<<<NG, 256, 0, stream>>>(knnres, out_d2, out_id, pcd, hist16, out_patch);
    scan_offs<<<NNODES / 4, 256, 0, stream>>>(hist16, offs);
    scatter_patch<<<NG, 256, 0, stream>>>(pcd, offs, out_patch);
}

// Round 13
// 133.981 us; speedup vs baseline: 1.0195x; 1.0052x over previous
//
#include <hip/hip_runtime.h>
#include <hip/hip_bf16.h>

#define NPTS   131072
#define NNODES 2048
#define KSEL   32

// ---- knn decomposition: 1024 blocks x 512 threads (8 waves) ----
#define TKNN   512                 // threads per knn block
#define WPB    8                   // waves per block
#define PPT    4                   // points per thread
#define NCHUNK 16                  // node chunks; chunk = wave-uniform -> s_load
#define CHN    (NNODES / NCHUNK)   // 128 nodes per chunk

// ---- grouping/scatter decomposition ----
#define GSZ    512                 // points per stability group
#define NG     (NPTS / GSZ)        // 256 groups

typedef unsigned int uint;
typedef unsigned short u16;
typedef unsigned long long u64;

// order-preserving fp32 -> u32 (handles tiny-negative cancellation results)
__device__ __forceinline__ uint f2ord(float d) {
    uint b = __float_as_uint(d);
    return (b & 0x80000000u) ? ~b : (b | 0x80000000u);
}
__device__ __forceinline__ float ord2f(uint t) {
    uint b = (t & 0x80000000u) ? (t ^ 0x80000000u) : ~t;
    return __uint_as_float(b);
}

// --- K0: init knnres to max keys; first 2048 threads also pack nodes {x,y,z,|n|^2} ---
__global__ __launch_bounds__(256) void prep_init(const float* __restrict__ nodes,
                                                 float4* __restrict__ n4,
                                                 u64* __restrict__ knnres) {
    int i = blockIdx.x * 256 + threadIdx.x;
    knnres[i] = ~0ull;
    if (i < NNODES) {
        float x = nodes[3 * i], y = nodes[3 * i + 1], z = nodes[3 * i + 2];
        // |n|^2 with numpy's mul-then-add rounding
        float nn = __fadd_rn(__fadd_rn(__fmul_rn(x, x), __fmul_rn(y, y)), __fmul_rn(z, z));
        n4[i] = make_float4(x, y, z, nn);
    }
}

// One node (scalars SX..SW) vs 4 points. d = (pp + fma(nz,z, fma(ny,y, nx*x))) + nn
// == ref (pp - 2*dot) + nn bit-exactly. Selects use 4 distinct SGPR-pair masks
// (no vcc serialization): 4 independent cmps, then 8 cndmasks on settled masks.
#define NODE4(SX, SY, SZ, SW) \
    "v_mul_f32 v0, " SX ", %[nx0]\n\t" \
    "v_mul_f32 v1, " SX ", %[nx1]\n\t" \
    "v_mul_f32 v2, " SX ", %[nx2]\n\t" \
    "v_mul_f32 v3, " SX ", %[nx3]\n\t" \
    "v_fma_f32 v0, " SY ", %[ny0], v0\n\t" \
    "v_fma_f32 v1, " SY ", %[ny1], v1\n\t" \
    "v_fma_f32 v2, " SY ", %[ny2], v2\n\t" \
    "v_fma_f32 v3, " SY ", %[ny3], v3\n\t" \
    "v_fma_f32 v0, " SZ ", %[nz0], v0\n\t" \
    "v_fma_f32 v1, " SZ ", %[nz1], v1\n\t" \
    "v_fma_f32 v2, " SZ ", %[nz2], v2\n\t" \
    "v_fma_f32 v3, " SZ ", %[nz3], v3\n\t" \
    "v_add_f32 v0, %[pp0], v0\n\t" \
    "v_add_f32 v1, %[pp1], v1\n\t" \
    "v_add_f32 v2, %[pp2], v2\n\t" \
    "v_add_f32 v3, %[pp3], v3\n\t" \
    "v_add_f32 v0, " SW ", v0\n\t" \
    "v_add_f32 v1, " SW ", v1\n\t" \
    "v_add_f32 v2, " SW ", v2\n\t" \
    "v_add_f32 v3, " SW ", v3\n\t" \
    "v_cmp_lt_f32 s[4:5], v0, %[b0]\n\t" \
    "v_cmp_lt_f32 s[6:7], v1, %[b1]\n\t" \
    "v_cmp_lt_f32 s[8:9], v2, %[b2]\n\t" \
    "v_cmp_lt_f32 s[10:11], v3, %[b3]\n\t" \
    "v_cndmask_b32 %[b0], %[b0], v0, s[4:5]\n\t" \
    "v_cndmask_b32 %[i0], %[i0], %[vj], s[4:5]\n\t" \
    "v_cndmask_b32 %[b1], %[b1], v1, s[6:7]\n\t" \
    "v_cndmask_b32 %[i1], %[i1], %[vj], s[6:7]\n\t" \
    "v_cndmask_b32 %[b2], %[b2], v2, s[8:9]\n\t" \
    "v_cndmask_b32 %[i2], %[i2], %[vj], s[8:9]\n\t" \
    "v_cndmask_b32 %[b3], %[b3], v3, s[10:11]\n\t" \
    "v_cndmask_b32 %[i3], %[i3], %[vj], s[10:11]\n\t" \
    "v_add_u32 %[vj], 1, %[vj]\n\t"

// --- K1: partial 1-NN, 4 pts/thread; slim dwordx8 ping-pong prefetch ---
// Buffers s[36:43]/s[44:51] (2 nodes each) -> 16 clobbered SGPRs (was 32),
// testing the SGPR-occupancy-cap theory. Strict < ascending jj =
// first-occurrence argmin; cross-chunk merge via u64 atomicMin keys.
__global__ __launch_bounds__(512) void knn_part(const float* __restrict__ pts,
                                                const float4* __restrict__ n4,
                                                u64* __restrict__ knnres) {
    int t    = threadIdx.x;
    int lane = t & 63;
    int w    = t >> 6;                        // wave in block
    int gw   = blockIdx.x * WPB + w;          // global wave id [0, 8192)
    int c    = __builtin_amdgcn_readfirstlane(gw & (NCHUNK - 1));  // wave-uniform chunk
    int pg   = gw >> 4;                       // point group [0, 512) of 256 points

    float pp[PPT], nx[PPT], ny[PPT], nz[PPT];
    #pragma unroll
    for (int q = 0; q < PPT; ++q) {
        int pid = pg * 256 + q * 64 + lane;   // consecutive lanes -> coalesced
        float p0 = pts[3 * pid], p1 = pts[3 * pid + 1], p2 = pts[3 * pid + 2];
        pp[q] = __fadd_rn(__fadd_rn(__fmul_rn(p0, p0), __fmul_rn(p1, p1)),
                          __fmul_rn(p2, p2));
        nx[q] = __fmul_rn(-2.0f, p0);         // exact
        ny[q] = __fmul_rn(-2.0f, p1);
        nz[q] = __fmul_rn(-2.0f, p2);
    }

    const float4* np = n4 + c * CHN;          // wave-uniform base (scalar)
    float b0 = 3.4e38f, b1 = 3.4e38f, b2 = 3.4e38f, b3 = 3.4e38f;
    uint  i0 = 0, i1 = 0, i2 = 0, i3 = 0;
    uint  vj = 0;

    // 32 iterations x 4 nodes. Each waitcnt drains a load issued one 2-node
    // compute block (~66 instr) earlier. Last iteration prefetches 64 B past
    // the chunk end (table has slack).
    asm volatile(
        "s_mov_b64 s[12:13], %[np]\n\t"
        "s_mov_b32 s14, 0\n\t"
        "s_load_dwordx8 s[36:43], s[12:13], 0x0\n\t"
        "1:\n\t"
        "s_waitcnt lgkmcnt(0)\n\t"
        "s_load_dwordx8 s[44:51], s[12:13], 0x20\n\t"
        NODE4("s36", "s37", "s38", "s39")
        NODE4("s40", "s41", "s42", "s43")
        "s_waitcnt lgkmcnt(0)\n\t"
        "s_load_dwordx8 s[36:43], s[12:13], 0x40\n\t"
        NODE4("s44", "s45", "s46", "s47")
        NODE4("s48", "s49", "s50", "s51")
        "s_add_u32 s12, s12, 0x40\n\t"
        "s_addc_u32 s13, s13, 0\n\t"
        "s_add_u32 s14, s14, 1\n\t"
        "s_cmp_lt_u32 s14, 32\n\t"
        "s_cbranch_scc1 1b\n\t"
        "s_waitcnt lgkmcnt(0)\n\t"            // drain dangling prefetch
        : [b0]"+v"(b0), [b1]"+v"(b1), [b2]"+v"(b2), [b3]"+v"(b3),
          [i0]"+v"(i0), [i1]"+v"(i1), [i2]"+v"(i2), [i3]"+v"(i3),
          [vj]"+v"(vj)
        : [np]"s"(np),
          [nx0]"v"(nx[0]), [nx1]"v"(nx[1]), [nx2]"v"(nx[2]), [nx3]"v"(nx[3]),
          [ny0]"v"(ny[0]), [ny1]"v"(ny[1]), [ny2]"v"(ny[2]), [ny3]"v"(ny[3]),
          [nz0]"v"(nz[0]), [nz1]"v"(nz[1]), [nz2]"v"(nz[2]), [nz3]"v"(nz[3]),
          [pp0]"v"(pp[0]), [pp1]"v"(pp[1]), [pp2]"v"(pp[2]), [pp3]"v"(pp[3])
        : "s4", "s5", "s6", "s7", "s8", "s9", "s10", "s11", "s12", "s13", "s14",
          "s36", "s37", "s38", "s39", "s40", "s41", "s42", "s43",
          "s44", "s45", "s46", "s47", "s48", "s49", "s50", "s51",
          "v0", "v1", "v2", "v3", "vcc", "scc", "memory");

    float best[PPT] = {b0, b1, b2, b3};
    uint  bi[PPT]   = {i0, i1, i2, i3};
    #pragma unroll
    for (int h = 0; h < PPT; ++h) {
        int pid = pg * 256 + h * 64 + lane;
        u64 key = ((u64)f2ord(best[h]) << 32) | (uint)(c * CHN + bi[h]);
        atomicMin(&knnres[pid], key);         // min key == (min d2, then min node idx)
    }
}

// --- K2: decode winners, write d2/id/pcd, per-group u16 histogram, zero patch ---
__global__ __launch_bounds__(256) void merge_hist(const u64* __restrict__ knnres,
                                                  float* __restrict__ out_d2,
                                                  float* __restrict__ out_id,
                                                  int* __restrict__ pcd,
                                                  u16* __restrict__ hist16,
                                                  float* __restrict__ patch) {
    __shared__ uint lh[NNODES];
    int g = blockIdx.x, t = threadIdx.x;
    patch[(size_t)g * 256 + t] = 0.0f;        // 256x256 = full 65536-float patch zeroed
    for (int i = t; i < NNODES; i += 256) lh[i] = 0;
    __syncthreads();

    #pragma unroll
    for (int q = 0; q < GSZ / 256; ++q) {
        int pid = g * GSZ + q * 256 + t;
        u64 key = knnres[pid];
        uint bi = (uint)key;                  // low 32: node index
        float d = ord2f((uint)(key >> 32));   // exact d2 decode
        atomicAdd(&lh[bi], 1u);
        out_d2[pid] = d;
        out_id[pid] = (float)bi;              // exact: bi < 2^24
        pcd[pid]    = (int)bi;
    }
    __syncthreads();
    for (int i = t; i < NNODES; i += 256)
        hist16[(size_t)g * NNODES + i] = (u16)lh[i];   // contiguous stores
}

// --- K3: per-node exclusive prefix across the 256 groups; offs in [node][group] ---
__global__ __launch_bounds__(256) void scan_offs(const u16* __restrict__ hist16,
                                                 uint* __restrict__ offs) {
    int t = threadIdx.x, lane = t & 63, wv = t >> 6;
    int node = blockIdx.x * 4 + wv;

    uint v0 = hist16[(size_t)(4 * lane + 0) * NNODES + node];
    uint v1 = hist16[(size_t)(4 * lane + 1) * NNODES + node];
    uint v2 = hist16[(size_t)(4 * lane + 2) * NNODES + node];
    uint v3 = hist16[(size_t)(4 * lane + 3) * NNODES + node];
    uint s = v0 + v1 + v2 + v3;
    uint a = s;
    #pragma unroll
    for (int d = 1; d < 64; d <<= 1) {
        uint y = __shfl_up(a, d, 64);
        if (lane >= d) a += y;
    }
    uint base = a - s;                        // exclusive across lanes
    uint4 o = make_uint4(base, base + v0, base + v0 + v1, base + v0 + v1 + v2);
    *(uint4*)(offs + (size_t)node * NG + 4 * lane) = o;   // contiguous 16B store
}

// --- K4: stable scatter of first-32 point indices per node ---
__global__ __launch_bounds__(256) void scatter_patch(const int* __restrict__ pcd,
                                                     const uint* __restrict__ offs,
                                                     float* __restrict__ patch) {
    __shared__ int ids[GSZ];
    int g = blockIdx.x, t = threadIdx.x;
    ids[t]       = pcd[g * GSZ + t];
    ids[256 + t] = pcd[g * GSZ + 256 + t];
    __syncthreads();

    int i0 = t, i1 = 256 + t;
    int my0 = ids[i0], my1 = ids[i1];
    int r0 = 0, r1 = 0;
    #pragma unroll 8
    for (int j = 0; j < GSZ; ++j) {
        int id = ids[j];                      // broadcast LDS read, conflict-free
        r0 += (j < i0 && id == my0) ? 1 : 0;
        r1 += (j < i1 && id == my1) ? 1 : 0;
    }
    uint rk0 = offs[(size_t)my0 * NG + g] + (uint)r0;
    uint rk1 = offs[(size_t)my1 * NG + g] + (uint)r1;
    if (rk0 < KSEL) patch[(size_t)my0 * KSEL + rk0] = (float)(g * GSZ + i0);
    if (rk1 < KSEL) patch[(size_t)my1 * KSEL + rk1] = (float)(g * GSZ + i1);
}

extern "C" void kernel_launch(void* const* d_in, const int* in_sizes, int n_in,
                              void* d_out, int out_size, void* d_ws, size_t ws_size,
                              hipStream_t stream) {
    const float* pts   = (const float*)d_in[0];
    const float* nodes = (const float*)d_in[1];

    float* out       = (float*)d_out;
    float* out_d2    = out;                   // 131072 floats
    float* out_id    = out + NPTS;            // 131072 floats
    float* out_patch = out + 2 * NPTS;        // 65536 floats

    // workspace: ~4.6 MB (n4 table has >=64B slack after it for the asm overshoot)
    char* ws = (char*)d_ws;
    u64*   knnres = (u64*) ws;                               // 1 MB   (131072 x u64)
    u16*   hist16 = (u16*) (ws + (1 << 20));                 // 1 MB   (256 x 2048 u16)
    uint*  offs   = (uint*) (ws + (2 << 20));                // 2 MB   (2048 x 256 u32)
    int*   pcd    = (int*)  (ws + (4 << 20));                // 512 KB
    float4* n4    = (float4*)(ws + (4 << 20) + (512 << 10)); // 32 KB + slack

    prep_init<<<NPTS / 256, 256, 0, stream>>>(nodes, n4, knnres);
    knn_part<<<(NPTS / 256 / NCHUNK) * NCHUNK * 2, TKNN, 0, stream>>>(pts, n4, knnres);
    merge_hist<<<NG, 256, 0, stream>>>(knnres, out_d2, out_id, pcd, hist16, out_patch);
    scan_offs<<<NNODES / 4, 256, 0, stream>>>(hist16, offs);
    scatter_patch<<<NG, 256, 0, stream>>>(pcd, offs, out_patch);
}